// Round 8
// baseline (894.403 us; speedup 1.0000x reference)
//
#include <hip/hip_runtime.h>
#include <hip/hip_bf16.h>
#include <math.h>

// ---------------------------------------------------------------------------
// EgoGNN round 7 (= round 5 resubmitted; rounds 6-7 were broker timeouts):
// round-3 design + one-line fix in agg40_lsm_k
// (both wave-halves were contributing to the softmax exp-sum after the
//  shfl_xor(32) combine -> denominator doubled -> uniform -log(2) offset,
//  absmax 0.6875 = log(2). Now only half 0 contributes.)
// ---------------------------------------------------------------------------

#define FEAT 128

// ---- CSR build -------------------------------------------------------------

__global__ __launch_bounds__(256) void hist_k(
    const int* __restrict__ dst, int* __restrict__ deg, int E)
{
    int e = blockIdx.x * 256 + threadIdx.x;
    if (e < E) atomicAdd(&deg[dst[e]], 1);
}

__global__ __launch_bounds__(256) void alloc_k(
    const int* __restrict__ deg, int* __restrict__ start,
    int* __restrict__ cursor, int* __restrict__ counter, int N)
{
    int v = blockIdx.x * 256 + threadIdx.x;
    if (v < N) {
        int d = deg[v];
        int s = atomicAdd(counter, d);
        start[v] = s;
        cursor[v] = s;
    }
}

__global__ __launch_bounds__(256) void fill_k(
    const int* __restrict__ src, const int* __restrict__ dst,
    int* __restrict__ cursor, int* __restrict__ col, int E)
{
    int e = blockIdx.x * 256 + threadIdx.x;
    if (e < E) {
        int p = atomicAdd(&cursor[dst[e]], 1);
        col[p] = src[e];
    }
}

// ---- Pull aggregation (128 feats): out[v] = scale*((SELF?x[v]:0) + sum x[col])
// One wave per node. Two 32-lane halves each process one edge per iteration;
// each half's 32 lanes x float4 = full 512B row. Halves combined by shfl_xor.
template<bool SELF>
__global__ __launch_bounds__(256) void csr_agg_k(
    const float* __restrict__ x, const int* __restrict__ col,
    const int* __restrict__ start, const int* __restrict__ deg,
    float* __restrict__ out, int N, float scale)
{
    int w = (blockIdx.x * 256 + threadIdx.x) >> 6;   // node id (wave-uniform)
    if (w >= N) return;
    int lane = threadIdx.x & 63;
    int half = lane >> 5;
    int q = lane & 31;          // float4 slot within row

    int s0 = start[w];
    int d  = deg[w];

    float4 acc = make_float4(0.f, 0.f, 0.f, 0.f);
    if (SELF && half == 0)
        acc = ((const float4*)(x + (size_t)w * FEAT))[q];

    for (int j = 0; j < d; j += 64) {
        int rem = d - j;
        int idx = (lane < rem) ? col[s0 + j + lane] : 0;
        int cnt = half ? min(32, max(rem - 32, 0)) : min(32, rem);
#pragma unroll 4
        for (int t = 0; t < cnt; ++t) {
            int s = __shfl(idx, t + (half << 5));
            float4 v = ((const float4*)(x + (size_t)s * FEAT))[q];
            acc.x += v.x; acc.y += v.y; acc.z += v.z; acc.w += v.w;
        }
    }
    // combine halves (lane i <-> i+32 hold the same feature slot q)
    acc.x += __shfl_xor(acc.x, 32);
    acc.y += __shfl_xor(acc.y, 32);
    acc.z += __shfl_xor(acc.z, 32);
    acc.w += __shfl_xor(acc.w, 32);

    if (half == 0) {
        float4 o = make_float4(acc.x * scale, acc.y * scale,
                               acc.z * scale, acc.w * scale);
        ((float4*)(out + (size_t)w * FEAT))[q] = o;
    }
}

// ---- Dense 128x128: Y = relu(X @ W + b) ------------------------------------
template<bool RELU>
__global__ __launch_bounds__(256, 2) void lin128_k(
    const float* __restrict__ X, const float* __restrict__ W,
    const float* __restrict__ b, float* __restrict__ Y, int nRows)
{
    __shared__ float Wl[FEAT * FEAT];   // 64 KiB
    __shared__ float Xl[32 * FEAT];     // 16 KiB
    int tid = threadIdx.x;

    const float4* Wv = (const float4*)W;
    float4* Wlv = (float4*)Wl;
#pragma unroll
    for (int i = 0; i < 16; ++i) Wlv[tid + i * 256] = Wv[tid + i * 256];

    int r0 = blockIdx.x * 32;
    const float4* Xv = (const float4*)(X + (size_t)r0 * FEAT);
    float4* Xlv = (float4*)Xl;
#pragma unroll
    for (int i = 0; i < 4; ++i) {
        int fi = tid + i * 256;
        int rr = fi >> 5;
        float4 z = make_float4(0.f, 0.f, 0.f, 0.f);
        Xlv[fi] = (r0 + rr < nRows) ? Xv[fi] : z;
    }
    __syncthreads();

    int tc = (tid & 31) * 4;
    int tr = (tid >> 5) * 4;

    float acc[4][4];
#pragma unroll
    for (int i = 0; i < 4; ++i)
#pragma unroll
        for (int j = 0; j < 4; ++j) acc[i][j] = 0.f;

    for (int k = 0; k < FEAT; ++k) {
        float4 wv = *(const float4*)&Wl[k * FEAT + tc];
        float xs[4];
#pragma unroll
        for (int i = 0; i < 4; ++i) xs[i] = Xl[(tr + i) * FEAT + k];
#pragma unroll
        for (int i = 0; i < 4; ++i) {
            acc[i][0] += xs[i] * wv.x;
            acc[i][1] += xs[i] * wv.y;
            acc[i][2] += xs[i] * wv.z;
            acc[i][3] += xs[i] * wv.w;
        }
    }

    float4 bv = *(const float4*)&b[tc];
#pragma unroll
    for (int i = 0; i < 4; ++i) {
        int r = r0 + tr + i;
        if (r < nRows) {
            float4 o;
            o.x = acc[i][0] + bv.x;
            o.y = acc[i][1] + bv.y;
            o.z = acc[i][2] + bv.z;
            o.w = acc[i][3] + bv.w;
            if (RELU) {
                o.x = fmaxf(o.x, 0.f); o.y = fmaxf(o.y, 0.f);
                o.z = fmaxf(o.z, 0.f); o.w = fmaxf(o.w, 0.f);
            }
            *(float4*)&Y[(size_t)r * FEAT + tc] = o;
        }
    }
}

// ---- Y40 = X @ W40 (no bias): one wave per row -----------------------------
__global__ __launch_bounds__(256) void lin40_k(
    const float* __restrict__ X, const float* __restrict__ W,
    float* __restrict__ Y, int nRows)
{
    __shared__ float Wl[FEAT * 40];
    int tid = threadIdx.x;
#pragma unroll
    for (int i = 0; i < 5; ++i)
        ((float4*)Wl)[tid + i * 256] = ((const float4*)W)[tid + i * 256];
    __syncthreads();

    int lane = tid & 63;
    int wv = tid >> 6;
    int row = blockIdx.x * 4 + wv;
    if (row >= nRows) return;

    const float* xr = X + (size_t)row * FEAT;
    float acc = 0.f;
    if (lane < 40) {
        for (int k = 0; k < FEAT; ++k) acc += xr[k] * Wl[k * 40 + lane];
        Y[(size_t)row * 40 + lane] = acc;
    }
}

// ---- Fused GIN-40 + bias + log_softmax -------------------------------------
// out[v] = log_softmax(y[v] + sum_j y[col[j]] + bias)
// Wave per node, two halves x (20 lanes x float2) per edge.
__global__ __launch_bounds__(256) void agg40_lsm_k(
    const float* __restrict__ y, const int* __restrict__ col,
    const int* __restrict__ start, const int* __restrict__ deg,
    const float* __restrict__ bias, float* __restrict__ out, int N)
{
    int w = (blockIdx.x * 256 + threadIdx.x) >> 6;
    if (w >= N) return;
    int lane = threadIdx.x & 63;
    int half = lane >> 5;
    int q = lane & 31;          // float2 slot; valid when q < 20

    int s0 = start[w];
    int d  = deg[w];

    float2 acc = make_float2(0.f, 0.f);
    if (half == 0 && q < 20)
        acc = ((const float2*)(y + (size_t)w * 40))[q];

    for (int j = 0; j < d; j += 64) {
        int rem = d - j;
        int idx = (lane < rem) ? col[s0 + j + lane] : 0;
        int cnt = half ? min(32, max(rem - 32, 0)) : min(32, rem);
        for (int t = 0; t < cnt; ++t) {
            int s = __shfl(idx, t + (half << 5));
            if (q < 20) {
                float2 v = ((const float2*)(y + (size_t)s * 40))[q];
                acc.x += v.x; acc.y += v.y;
            }
        }
    }
    acc.x += __shfl_xor(acc.x, 32);
    acc.y += __shfl_xor(acc.y, 32);

    if (q < 20) {
        acc.x += bias[2 * q];
        acc.y += bias[2 * q + 1];
    }
    float mx = (q < 20) ? fmaxf(acc.x, acc.y) : -INFINITY;
#pragma unroll
    for (int off = 1; off <= 32; off <<= 1) mx = fmaxf(mx, __shfl_xor(mx, off));
    // FIX: after the xor-combine BOTH halves hold the full sum; only half 0
    // may contribute to the exp-sum, else the denominator doubles (-log2 bug).
    float ex = (half == 0 && q < 20) ? (expf(acc.x - mx) + expf(acc.y - mx)) : 0.f;
#pragma unroll
    for (int off = 1; off <= 32; off <<= 1) ex += __shfl_xor(ex, off);
    float ls = logf(ex);

    if (half == 0 && q < 20) {
        float2 o = make_float2(acc.x - mx - ls, acc.y - mx - ls);
        ((float2*)(out + (size_t)w * 40))[q] = o;
    }
}

// ---------------------------------------------------------------------------

extern "C" void kernel_launch(void* const* d_in, const int* in_sizes, int n_in,
                              void* d_out, int out_size, void* d_ws, size_t ws_size,
                              hipStream_t stream) {
    const float* x_in = (const float*)d_in[0];
    const int* ei_reg = (const int*)d_in[1];   // row0=src, row1=dst
    const int* ei_ego = (const int*)d_in[2];   // row0=dst, row1=src
    const float* W1  = (const float*)d_in[3];
    const float* b1  = (const float*)d_in[4];
    const float* Wg1 = (const float*)d_in[5];
    const float* bg1 = (const float*)d_in[6];
    const float* W2  = (const float*)d_in[7];
    const float* b2  = (const float*)d_in[8];
    const float* Wg2 = (const float*)d_in[9];
    const float* bg2 = (const float*)d_in[10];
    float* out = (float*)d_out;

    const int N = in_sizes[0] / FEAT;          // 50000
    const int E_reg = in_sizes[1] / 2;         // 800000
    const int E_ego = in_sizes[2] / 2;         // 1600000
    const float inv_n = 1.0f / (float)N;

    // ---- workspace layout ----
    float* B0   = (float*)d_ws;
    float* B1   = B0 + (size_t)N * FEAT;
    int* colE   = (int*)(B1 + (size_t)N * FEAT);   // E_ego
    int* colR   = colE + E_ego;                    // E_reg
    int* degE   = colR + E_reg;                    // N   } contiguous
    int* degR   = degE + N;                        // N   } zero-init
    int* cnt    = degR + N;                        // 2   } region
    int* stE    = cnt + 2;
    int* curE   = stE + N;
    int* stR    = curE + N;
    int* curR   = stR + N;
    float* Y40  = B0;                              // alias: B0 free at final

    const int ego_eb = (E_ego + 255) / 256;
    const int reg_eb = (E_reg + 255) / 256;
    const int nb     = (N + 255) / 256;
    const int agg_b  = (N + 3) / 4;      // wave per node, 4 waves/block
    const int lin_b  = (N + 31) / 32;

    // ---- build CSRs (reused by both layers) ----
    hipMemsetAsync(degE, 0, (2 * (size_t)N + 2) * sizeof(int), stream);
    hist_k<<<ego_eb, 256, 0, stream>>>(ei_ego, degE, E_ego);
    hist_k<<<reg_eb, 256, 0, stream>>>(ei_reg + E_reg, degR, E_reg);
    alloc_k<<<nb, 256, 0, stream>>>(degE, stE, curE, cnt + 0, N);
    alloc_k<<<nb, 256, 0, stream>>>(degR, stR, curR, cnt + 1, N);
    fill_k<<<ego_eb, 256, 0, stream>>>(ei_ego + E_ego, ei_ego, curE, colE, E_ego);
    fill_k<<<reg_eb, 256, 0, stream>>>(ei_reg, ei_reg + E_reg, curR, colR, E_reg);

    // ---- Layer 1 ----
    csr_agg_k<false><<<agg_b, 256, 0, stream>>>(x_in, colE, stE, degE, B0, N, inv_n);
    lin128_k<true><<<lin_b, 256, 0, stream>>>(B0, W1, b1, B1, N);
    csr_agg_k<true><<<agg_b, 256, 0, stream>>>(B1, colR, stR, degR, B0, N, 1.0f);
    lin128_k<true><<<lin_b, 256, 0, stream>>>(B0, Wg1, bg1, B1, N);

    // ---- Layer 2 ----
    csr_agg_k<false><<<agg_b, 256, 0, stream>>>(B1, colE, stE, degE, B0, N, inv_n);
    lin128_k<true><<<lin_b, 256, 0, stream>>>(B0, W2, b2, B1, N);
    // final GIN swapped: Y40 = B1 @ Wg2 ; out = lsm(Y40[v] + sum Y40[col] + bg2)
    lin40_k<<<agg_b, 256, 0, stream>>>(B1, Wg2, Y40, N);
    agg40_lsm_k<<<agg_b, 256, 0, stream>>>(Y40, colR, stR, degR, bg2, out, N);
}

// Round 10
// 761.241 us; speedup vs baseline: 1.1749x; 1.1749x over previous
//
#include <hip/hip_runtime.h>
#include <hip/hip_bf16.h>
#include <math.h>

// ---------------------------------------------------------------------------
// EgoGNN round 10 (= round 9 resubmitted after broker timeout):
// bf16 activation storage end-to-end (output magnitudes are ~ -log(40) ± 1e-7,
// threshold 7.4e-2 -> bf16 rounding is harmless).
//  - aggs gather bf16 rows: 16 lanes x 16B = 256B row, 4 edges/wave-iter
//  - lin128 stages bf16 -> f32 LDS (proven inner loop unchanged), writes bf16
//  - fill_k unchanged (random-line amplification needs a sort; next round)
// ---------------------------------------------------------------------------

#define FEAT 128

typedef unsigned short ushort_t;
typedef unsigned int uint_t;

__device__ inline float bflo(uint_t u) { return __uint_as_float(u << 16); }
__device__ inline float bfhi(uint_t u) { return __uint_as_float(u & 0xFFFF0000u); }
__device__ inline ushort_t f2bf(float f) {
    union { float f; uint_t u; } c; c.f = f;
    uint_t u = c.u;
    return (ushort_t)((u + 0x7FFFu + ((u >> 16) & 1u)) >> 16);   // RNE
}
__device__ inline uint_t pack2(float lo, float hi) {
    return (uint_t)f2bf(lo) | ((uint_t)f2bf(hi) << 16);
}

// ---- cast x_in (f32) -> bf16 ----------------------------------------------
__global__ __launch_bounds__(256) void cast_k(
    const float* __restrict__ in, ushort_t* __restrict__ out, int n4)
{
    int i = blockIdx.x * 256 + threadIdx.x;
    if (i >= n4) return;
    float4 v = ((const float4*)in)[i];
    ushort4 o;
    o.x = f2bf(v.x); o.y = f2bf(v.y); o.z = f2bf(v.z); o.w = f2bf(v.w);
    ((ushort4*)out)[i] = o;
}

// ---- CSR build -------------------------------------------------------------

__global__ __launch_bounds__(256) void hist_k(
    const int* __restrict__ dst, int* __restrict__ deg, int E)
{
    int e = blockIdx.x * 256 + threadIdx.x;
    if (e < E) atomicAdd(&deg[dst[e]], 1);
}

__global__ __launch_bounds__(256) void alloc_k(
    const int* __restrict__ deg, int* __restrict__ start,
    int* __restrict__ cursor, int* __restrict__ counter, int N)
{
    int v = blockIdx.x * 256 + threadIdx.x;
    if (v < N) {
        int d = deg[v];
        int s = atomicAdd(counter, d);
        start[v] = s;
        cursor[v] = s;
    }
}

__global__ __launch_bounds__(256) void fill_k(
    const int* __restrict__ src, const int* __restrict__ dst,
    int* __restrict__ cursor, int* __restrict__ col, int E)
{
    int e = blockIdx.x * 256 + threadIdx.x;
    if (e < E) {
        int p = atomicAdd(&cursor[dst[e]], 1);
        col[p] = src[e];
    }
}

// ---- Pull aggregation, bf16 in/out, f32 accumulate -------------------------
// out[v] = bf16( scale * ((SELF ? x[v] : 0) + sum_j x[col[j]]) )
// One wave per node; 4 quarter-waves x (16 lanes x 16B=8bf16) -> 4 edges/iter.
template<bool SELF>
__global__ __launch_bounds__(256) void csr_agg_bf_k(
    const ushort_t* __restrict__ x, const int* __restrict__ col,
    const int* __restrict__ start, const int* __restrict__ deg,
    ushort_t* __restrict__ out, int N, float scale)
{
    int w = (blockIdx.x * 256 + threadIdx.x) >> 6;   // node id (wave-uniform)
    if (w >= N) return;
    int lane = threadIdx.x & 63;
    int quarter = lane >> 4;      // 0..3
    int q = lane & 15;            // 16B slot: feats 8q..8q+7

    int s0 = start[w];
    int d  = deg[w];

    float a0=0.f,a1=0.f,a2=0.f,a3=0.f,a4=0.f,a5=0.f,a6=0.f,a7=0.f;
    if (SELF && quarter == 0) {
        uint4 u = ((const uint4*)(x + (size_t)w * FEAT))[q];
        a0 = bflo(u.x); a1 = bfhi(u.x);
        a2 = bflo(u.y); a3 = bfhi(u.y);
        a4 = bflo(u.z); a5 = bfhi(u.z);
        a6 = bflo(u.w); a7 = bfhi(u.w);
    }

    int base = quarter << 4;
    for (int j = 0; j < d; j += 64) {
        int rem = d - j;
        int idx = (lane < rem) ? col[s0 + j + lane] : 0;
        int cnt = min(16, max(rem - base, 0));
#pragma unroll 4
        for (int t = 0; t < cnt; ++t) {
            int s = __shfl(idx, base + t);
            uint4 u = ((const uint4*)(x + (size_t)s * FEAT))[q];
            a0 += bflo(u.x); a1 += bfhi(u.x);
            a2 += bflo(u.y); a3 += bfhi(u.y);
            a4 += bflo(u.z); a5 += bfhi(u.z);
            a6 += bflo(u.w); a7 += bfhi(u.w);
        }
    }
    // combine quarters: lanes {l, l^16, l^32, l^48} hold same feature slot q
    a0 += __shfl_xor(a0, 16); a0 += __shfl_xor(a0, 32);
    a1 += __shfl_xor(a1, 16); a1 += __shfl_xor(a1, 32);
    a2 += __shfl_xor(a2, 16); a2 += __shfl_xor(a2, 32);
    a3 += __shfl_xor(a3, 16); a3 += __shfl_xor(a3, 32);
    a4 += __shfl_xor(a4, 16); a4 += __shfl_xor(a4, 32);
    a5 += __shfl_xor(a5, 16); a5 += __shfl_xor(a5, 32);
    a6 += __shfl_xor(a6, 16); a6 += __shfl_xor(a6, 32);
    a7 += __shfl_xor(a7, 16); a7 += __shfl_xor(a7, 32);

    if (quarter == 0) {
        uint4 o;
        o.x = pack2(a0 * scale, a1 * scale);
        o.y = pack2(a2 * scale, a3 * scale);
        o.z = pack2(a4 * scale, a5 * scale);
        o.w = pack2(a6 * scale, a7 * scale);
        ((uint4*)(out + (size_t)w * FEAT))[q] = o;
    }
}

// ---- Dense 128x128: Y = bf16(relu(X @ W + b)), X bf16, W/b f32 -------------
__global__ __launch_bounds__(256, 2) void lin128_bf_k(
    const ushort_t* __restrict__ X, const float* __restrict__ W,
    const float* __restrict__ b, ushort_t* __restrict__ Y, int nRows)
{
    __shared__ float Wl[FEAT * FEAT];   // 64 KiB
    __shared__ float Xl[32 * FEAT];     // 16 KiB
    int tid = threadIdx.x;

    const float4* Wv = (const float4*)W;
    float4* Wlv = (float4*)Wl;
#pragma unroll
    for (int i = 0; i < 16; ++i) Wlv[tid + i * 256] = Wv[tid + i * 256];

    int r0 = blockIdx.x * 32;
    const uint4* Xv = (const uint4*)(X + (size_t)r0 * FEAT);  // 8 bf16 / uint4
#pragma unroll
    for (int i = 0; i < 2; ++i) {
        int fi = tid + i * 256;          // [0,512): rr = fi>>4, col8 = (fi&15)*8
        int rr = fi >> 4;
        int c8 = (fi & 15) * 8;
        float v0=0,v1=0,v2=0,v3=0,v4=0,v5=0,v6=0,v7=0;
        if (r0 + rr < nRows) {
            uint4 u = Xv[fi];
            v0 = bflo(u.x); v1 = bfhi(u.x);
            v2 = bflo(u.y); v3 = bfhi(u.y);
            v4 = bflo(u.z); v5 = bfhi(u.z);
            v6 = bflo(u.w); v7 = bfhi(u.w);
        }
        float* p = &Xl[rr * FEAT + c8];
        p[0]=v0; p[1]=v1; p[2]=v2; p[3]=v3; p[4]=v4; p[5]=v5; p[6]=v6; p[7]=v7;
    }
    __syncthreads();

    int tc = (tid & 31) * 4;
    int tr = (tid >> 5) * 4;

    float acc[4][4];
#pragma unroll
    for (int i = 0; i < 4; ++i)
#pragma unroll
        for (int j = 0; j < 4; ++j) acc[i][j] = 0.f;

    for (int k = 0; k < FEAT; ++k) {
        float4 wv = *(const float4*)&Wl[k * FEAT + tc];
        float xs[4];
#pragma unroll
        for (int i = 0; i < 4; ++i) xs[i] = Xl[(tr + i) * FEAT + k];
#pragma unroll
        for (int i = 0; i < 4; ++i) {
            acc[i][0] += xs[i] * wv.x;
            acc[i][1] += xs[i] * wv.y;
            acc[i][2] += xs[i] * wv.z;
            acc[i][3] += xs[i] * wv.w;
        }
    }

    float4 bv = *(const float4*)&b[tc];
#pragma unroll
    for (int i = 0; i < 4; ++i) {
        int r = r0 + tr + i;
        if (r < nRows) {
            float ox = fmaxf(acc[i][0] + bv.x, 0.f);
            float oy = fmaxf(acc[i][1] + bv.y, 0.f);
            float oz = fmaxf(acc[i][2] + bv.z, 0.f);
            float ow = fmaxf(acc[i][3] + bv.w, 0.f);
            ushort4 o;
            o.x = f2bf(ox); o.y = f2bf(oy); o.z = f2bf(oz); o.w = f2bf(ow);
            *(ushort4*)&Y[(size_t)r * FEAT + tc] = o;
        }
    }
}

// ---- Y40 = bf16(X @ W40), X bf16: one wave per row -------------------------
__global__ __launch_bounds__(256) void lin40_bf_k(
    const ushort_t* __restrict__ X, const float* __restrict__ W,
    ushort_t* __restrict__ Y, int nRows)
{
    __shared__ float Wl[FEAT * 40];
    int tid = threadIdx.x;
#pragma unroll
    for (int i = 0; i < 5; ++i)
        ((float4*)Wl)[tid + i * 256] = ((const float4*)W)[tid + i * 256];
    __syncthreads();

    int lane = tid & 63;
    int wv = tid >> 6;
    int row = blockIdx.x * 4 + wv;
    if (row >= nRows) return;

    const ushort_t* xr = X + (size_t)row * FEAT;
    float acc = 0.f;
    if (lane < 40) {
        for (int k = 0; k < FEAT; ++k) {
            float xk = __uint_as_float(((uint_t)xr[k]) << 16);
            acc += xk * Wl[k * 40 + lane];
        }
        Y[(size_t)row * 40 + lane] = f2bf(acc);
    }
}

// ---- Fused GIN-40 + bias + log_softmax, y bf16 -----------------------------
// out[v] = log_softmax(y[v] + sum_j y[col[j]] + bias)   (f32 out)
__global__ __launch_bounds__(256) void agg40_lsm_k(
    const ushort_t* __restrict__ y, const int* __restrict__ col,
    const int* __restrict__ start, const int* __restrict__ deg,
    const float* __restrict__ bias, float* __restrict__ out, int N)
{
    int w = (blockIdx.x * 256 + threadIdx.x) >> 6;
    if (w >= N) return;
    int lane = threadIdx.x & 63;
    int half = lane >> 5;
    int q = lane & 31;          // uint slot (2 bf16); valid when q < 20

    int s0 = start[w];
    int d  = deg[w];

    float ax = 0.f, ay = 0.f;
    if (half == 0 && q < 20) {
        uint_t u = ((const uint_t*)(y + (size_t)w * 40))[q];
        ax = bflo(u); ay = bfhi(u);
    }

    for (int j = 0; j < d; j += 64) {
        int rem = d - j;
        int idx = (lane < rem) ? col[s0 + j + lane] : 0;
        int cnt = half ? min(32, max(rem - 32, 0)) : min(32, rem);
        for (int t = 0; t < cnt; ++t) {
            int s = __shfl(idx, t + (half << 5));
            if (q < 20) {
                uint_t u = ((const uint_t*)(y + (size_t)s * 40))[q];
                ax += bflo(u); ay += bfhi(u);
            }
        }
    }
    ax += __shfl_xor(ax, 32);
    ay += __shfl_xor(ay, 32);

    if (q < 20) {
        ax += bias[2 * q];
        ay += bias[2 * q + 1];
    }
    float mx = (q < 20) ? fmaxf(ax, ay) : -INFINITY;
#pragma unroll
    for (int off = 1; off <= 32; off <<= 1) mx = fmaxf(mx, __shfl_xor(mx, off));
    // only half 0 contributes to the exp-sum (both halves hold the full row)
    float ex = (half == 0 && q < 20) ? (expf(ax - mx) + expf(ay - mx)) : 0.f;
#pragma unroll
    for (int off = 1; off <= 32; off <<= 1) ex += __shfl_xor(ex, off);
    float ls = logf(ex);

    if (half == 0 && q < 20) {
        float2 o = make_float2(ax - mx - ls, ay - mx - ls);
        ((float2*)(out + (size_t)w * 40))[q] = o;
    }
}

// ---------------------------------------------------------------------------

extern "C" void kernel_launch(void* const* d_in, const int* in_sizes, int n_in,
                              void* d_out, int out_size, void* d_ws, size_t ws_size,
                              hipStream_t stream) {
    const float* x_in = (const float*)d_in[0];
    const int* ei_reg = (const int*)d_in[1];   // row0=src, row1=dst
    const int* ei_ego = (const int*)d_in[2];   // row0=dst, row1=src
    const float* W1  = (const float*)d_in[3];
    const float* b1  = (const float*)d_in[4];
    const float* Wg1 = (const float*)d_in[5];
    const float* bg1 = (const float*)d_in[6];
    const float* W2  = (const float*)d_in[7];
    const float* b2  = (const float*)d_in[8];
    const float* Wg2 = (const float*)d_in[9];
    const float* bg2 = (const float*)d_in[10];
    float* out = (float*)d_out;

    const int N = in_sizes[0] / FEAT;          // 50000
    const int E_reg = in_sizes[1] / 2;         // 800000
    const int E_ego = in_sizes[2] / 2;         // 1600000
    const float inv_n = 1.0f / (float)N;

    // ---- workspace layout (bf16 activations) ----
    ushort_t* Xb  = (ushort_t*)d_ws;                 // N*128 bf16
    ushort_t* B0  = Xb + (size_t)N * FEAT;           // N*128 bf16
    ushort_t* B1  = B0 + (size_t)N * FEAT;           // N*128 bf16
    ushort_t* Y40 = B1 + (size_t)N * FEAT;           // N*40  bf16
    int* colE = (int*)(Y40 + (size_t)N * 40 + ((size_t)N * 40 % 2)); // align 4B
    int* colR = colE + E_ego;
    int* degE = colR + E_reg;                        // N } contiguous zero-init
    int* degR = degE + N;                            // N }
    int* cnt  = degR + N;                            // 2 }
    int* stE  = cnt + 2;
    int* curE = stE + N;
    int* stR  = curE + N;
    int* curR = stR + N;

    const int ego_eb = (E_ego + 255) / 256;
    const int reg_eb = (E_reg + 255) / 256;
    const int nb     = (N + 255) / 256;
    const int agg_b  = (N + 3) / 4;      // wave per node, 4 waves/block
    const int lin_b  = (N + 31) / 32;
    const int cast_b = ((N * FEAT / 4) + 255) / 256;

    // ---- build CSRs (reused by both layers) + cast input ----
    hipMemsetAsync(degE, 0, (2 * (size_t)N + 2) * sizeof(int), stream);
    cast_k<<<cast_b, 256, 0, stream>>>(x_in, Xb, N * FEAT / 4);
    hist_k<<<ego_eb, 256, 0, stream>>>(ei_ego, degE, E_ego);
    hist_k<<<reg_eb, 256, 0, stream>>>(ei_reg + E_reg, degR, E_reg);
    alloc_k<<<nb, 256, 0, stream>>>(degE, stE, curE, cnt + 0, N);
    alloc_k<<<nb, 256, 0, stream>>>(degR, stR, curR, cnt + 1, N);
    fill_k<<<ego_eb, 256, 0, stream>>>(ei_ego + E_ego, ei_ego, curE, colE, E_ego);
    fill_k<<<reg_eb, 256, 0, stream>>>(ei_reg, ei_reg + E_reg, curR, colR, E_reg);

    // ---- Layer 1 ----
    csr_agg_bf_k<false><<<agg_b, 256, 0, stream>>>(Xb, colE, stE, degE, B0, N, inv_n);
    lin128_bf_k<<<lin_b, 256, 0, stream>>>(B0, W1, b1, B1, N);
    csr_agg_bf_k<true><<<agg_b, 256, 0, stream>>>(B1, colR, stR, degR, B0, N, 1.0f);
    lin128_bf_k<<<lin_b, 256, 0, stream>>>(B0, Wg1, bg1, B1, N);

    // ---- Layer 2 ----
    csr_agg_bf_k<false><<<agg_b, 256, 0, stream>>>(B1, colE, stE, degE, B0, N, inv_n);
    lin128_bf_k<<<lin_b, 256, 0, stream>>>(B0, W2, b2, B1, N);
    // final GIN swapped: Y40 = B1 @ Wg2 ; out = lsm(Y40[v] + sum Y40[col] + bg2)
    lin40_bf_k<<<agg_b, 256, 0, stream>>>(B1, Wg2, Y40, N);
    agg40_lsm_k<<<agg_b, 256, 0, stream>>>(Y40, colR, stR, degR, bg2, out, N);
}